// Round 1
// baseline (65.874 us; speedup 1.0000x reference)
//
#include <hip/hip_runtime.h>
#include <math.h>

#define BB 32
#define SS 2048
#define DD 512

// Kernel 1: u[b,d] = sum_e hidden[b,e] * W[e,d]   (bias dropped: softmax shift-invariant)
__global__ void __launch_bounds__(256) compute_u_kernel(
    const float* __restrict__ hidden, const float* __restrict__ W,
    float* __restrict__ u) {
    const int b = blockIdx.x;
    __shared__ float h_s[DD];
    for (int i = threadIdx.x; i < DD; i += 256)
        h_s[i] = hidden[b * DD + i];
    __syncthreads();

    const int t = threadIdx.x;            // 256 threads, 2 adjacent d each
    float acc0 = 0.f, acc1 = 0.f;
    const float2* W2 = (const float2*)W;  // W[e, 2t], W[e, 2t+1]
    #pragma unroll 4
    for (int e = 0; e < DD; ++e) {
        float he = h_s[e];                 // LDS broadcast (free)
        float2 w = W2[e * (DD / 2) + t];   // coalesced 2 KB per iter
        acc0 = fmaf(he, w.x, acc0);
        acc1 = fmaf(he, w.y, acc1);
    }
    float2* u2 = (float2*)(u + b * DD);
    u2[t] = make_float2(acc0, acc1);
}

// Kernel 2: logits[b,s] = dot(enc[b,s,:], u[b,:])
// grid = (blocks_per_batch, B), block = 256 (4 waves). Each wave owns rows
// strided by total waves-per-batch. Lane l holds u[b, 8l..8l+7] in regs.
__global__ void __launch_bounds__(256) scores_kernel(
    const float* __restrict__ enc, const float* __restrict__ u,
    float* __restrict__ logits) {
    const int b    = blockIdx.y;
    const int lane = threadIdx.x & 63;
    const int wv   = threadIdx.x >> 6;

    const float4* uv = (const float4*)(u + b * DD);
    const float4  u0 = uv[lane * 2 + 0];
    const float4  u1 = uv[lane * 2 + 1];

    const int waves_per_b = gridDim.x * 4;
    const int wave_id     = blockIdx.x * 4 + wv;
    const float4* encb = (const float4*)(enc + (size_t)b * SS * DD);

    for (int s = wave_id; s < SS; s += waves_per_b) {
        const float4* row = encb + (size_t)s * (DD / 4);
        float4 e0 = row[lane * 2 + 0];     // 64 lanes x 32 B contiguous
        float4 e1 = row[lane * 2 + 1];
        float acc = e0.x * u0.x + e0.y * u0.y + e0.z * u0.z + e0.w * u0.w
                  + e1.x * u1.x + e1.y * u1.y + e1.z * u1.z + e1.w * u1.w;
        #pragma unroll
        for (int off = 32; off > 0; off >>= 1)
            acc += __shfl_xor(acc, off, 64);
        if (lane == 0) logits[b * SS + s] = acc;
    }
}

// Kernel 3: in-place softmax over S per batch. One block (256 thr) per batch.
__global__ void __launch_bounds__(256) softmax_kernel(float* __restrict__ io) {
    const int b = blockIdx.x;
    const int t = threadIdx.x;
    const int lane = t & 63, wv = t >> 6;
    float* p = io + b * SS;

    float vals[8];
    float m = -INFINITY;
    #pragma unroll
    for (int i = 0; i < 8; ++i) {
        vals[i] = p[t + i * 256];          // coalesced
        m = fmaxf(m, vals[i]);
    }
    #pragma unroll
    for (int off = 32; off > 0; off >>= 1)
        m = fmaxf(m, __shfl_xor(m, off, 64));

    __shared__ float red_m[4];
    __shared__ float red_s[4];
    if (lane == 0) red_m[wv] = m;
    __syncthreads();
    m = fmaxf(fmaxf(red_m[0], red_m[1]), fmaxf(red_m[2], red_m[3]));

    float sum = 0.f;
    #pragma unroll
    for (int i = 0; i < 8; ++i) {
        vals[i] = __expf(vals[i] - m);
        sum += vals[i];
    }
    #pragma unroll
    for (int off = 32; off > 0; off >>= 1)
        sum += __shfl_xor(sum, off, 64);
    if (lane == 0) red_s[wv] = sum;
    __syncthreads();
    sum = red_s[0] + red_s[1] + red_s[2] + red_s[3];

    const float inv = 1.f / sum;
    #pragma unroll
    for (int i = 0; i < 8; ++i)
        p[t + i * 256] = vals[i] * inv;
}

extern "C" void kernel_launch(void* const* d_in, const int* in_sizes, int n_in,
                              void* d_out, int out_size, void* d_ws, size_t ws_size,
                              hipStream_t stream) {
    const float* hidden = (const float*)d_in[0];   // [B,1,D]
    const float* enc    = (const float*)d_in[1];   // [B,S,D]
    const float* W      = (const float*)d_in[2];   // [D,D] (W[e,d])
    // d_in[3] = bias: adds a per-batch constant to all logits -> softmax-invariant, unused.
    float* out = (float*)d_out;                    // [B,1,S] fp32
    float* u   = (float*)d_ws;                     // B*D floats = 64 KB scratch

    compute_u_kernel<<<dim3(BB), dim3(256), 0, stream>>>(hidden, W, u);
    scores_kernel<<<dim3(64, BB), dim3(256), 0, stream>>>(enc, u, out);
    softmax_kernel<<<dim3(BB), dim3(256), 0, stream>>>(out);
}

// Round 2
// 34.874 us; speedup vs baseline: 1.8889x; 1.8889x over previous
//
#include <hip/hip_runtime.h>
#include <math.h>

#define BB 32
#define SS 2048
#define DD 512
#define ECHUNKS 8   // e-dimension split for compute_u parallelism

// Kernel 1: partial u. part[k][b][d] = sum_{e in chunk k} hidden[b,e] * W[e,d]
// Bias dropped entirely: it adds a per-batch constant to every logit,
// which softmax is invariant to.
// grid = (ECHUNKS, B), block = 256. Thread t owns d-pair (2t, 2t+1).
__global__ void __launch_bounds__(256) compute_u_partial(
    const float* __restrict__ hidden, const float* __restrict__ W,
    float* __restrict__ part) {
    const int k = blockIdx.x;
    const int b = blockIdx.y;
    __shared__ float h_s[DD / ECHUNKS];
    if (threadIdx.x < DD / ECHUNKS)
        h_s[threadIdx.x] = hidden[b * DD + k * (DD / ECHUNKS) + threadIdx.x];
    __syncthreads();

    const int t = threadIdx.x;
    float acc0 = 0.f, acc1 = 0.f;
    const float2* W2 = (const float2*)W;
    #pragma unroll 8
    for (int i = 0; i < DD / ECHUNKS; ++i) {
        const int e = k * (DD / ECHUNKS) + i;
        const float he = h_s[i];
        const float2 w = W2[(size_t)e * (DD / 2) + t];  // 2 KB coalesced per iter
        acc0 = fmaf(he, w.x, acc0);
        acc1 = fmaf(he, w.y, acc1);
    }
    ((float2*)(part + (size_t)(k * BB + b) * DD))[t] = make_float2(acc0, acc1);
}

// Kernel 2: logits[b,s] = dot(enc[b,s,:], u[b,:]) with u summed from partials.
// grid = (64, B), block = 256 (4 waves). Lane l holds u[b, 8l..8l+7] in regs.
__global__ void __launch_bounds__(256) scores_kernel(
    const float* __restrict__ enc, const float* __restrict__ part,
    float* __restrict__ logits) {
    const int b    = blockIdx.y;
    const int lane = threadIdx.x & 63;
    const int wv   = threadIdx.x >> 6;

    // Sum the 8 e-chunk partials into this lane's u fragment (L1/L2 hits;
    // issued once, overlaps with first enc loads).
    float4 u0 = make_float4(0.f, 0.f, 0.f, 0.f);
    float4 u1 = make_float4(0.f, 0.f, 0.f, 0.f);
    #pragma unroll
    for (int k = 0; k < ECHUNKS; ++k) {
        const float4* pk = (const float4*)(part + (size_t)(k * BB + b) * DD);
        const float4 a = pk[lane * 2 + 0];
        const float4 c = pk[lane * 2 + 1];
        u0.x += a.x; u0.y += a.y; u0.z += a.z; u0.w += a.w;
        u1.x += c.x; u1.y += c.y; u1.z += c.z; u1.w += c.w;
    }

    const int waves_per_b = gridDim.x * 4;
    const int wave_id     = blockIdx.x * 4 + wv;
    const float4* encb = (const float4*)(enc + (size_t)b * SS * DD);

    for (int s = wave_id; s < SS; s += waves_per_b) {
        const float4* row = encb + (size_t)s * (DD / 4);
        float4 e0 = row[lane * 2 + 0];   // 64 lanes x 32 B = full 2 KB row
        float4 e1 = row[lane * 2 + 1];
        float acc = e0.x * u0.x + e0.y * u0.y + e0.z * u0.z + e0.w * u0.w
                  + e1.x * u1.x + e1.y * u1.y + e1.z * u1.z + e1.w * u1.w;
        #pragma unroll
        for (int off = 32; off > 0; off >>= 1)
            acc += __shfl_xor(acc, off, 64);
        if (lane == 0) logits[b * SS + s] = acc;
    }
}

// Kernel 3: in-place softmax over S per batch. One block (512 thr, 8 waves),
// float4 per thread: 512*4 = 2048 = SS.
__global__ void __launch_bounds__(512) softmax_kernel(float* __restrict__ io) {
    const int b = blockIdx.x;
    const int t = threadIdx.x;
    const int lane = t & 63, wv = t >> 6;
    float4* p = (float4*)(io + b * SS);

    float4 v = p[t];
    float m = fmaxf(fmaxf(v.x, v.y), fmaxf(v.z, v.w));
    #pragma unroll
    for (int off = 32; off > 0; off >>= 1)
        m = fmaxf(m, __shfl_xor(m, off, 64));

    __shared__ float red_m[8];
    __shared__ float red_s[8];
    if (lane == 0) red_m[wv] = m;
    __syncthreads();
    m = red_m[0];
    #pragma unroll
    for (int i = 1; i < 8; ++i) m = fmaxf(m, red_m[i]);

    v.x = __expf(v.x - m);
    v.y = __expf(v.y - m);
    v.z = __expf(v.z - m);
    v.w = __expf(v.w - m);
    float sum = v.x + v.y + v.z + v.w;
    #pragma unroll
    for (int off = 32; off > 0; off >>= 1)
        sum += __shfl_xor(sum, off, 64);
    if (lane == 0) red_s[wv] = sum;
    __syncthreads();
    sum = 0.f;
    #pragma unroll
    for (int i = 0; i < 8; ++i) sum += red_s[i];

    const float inv = 1.f / sum;
    v.x *= inv; v.y *= inv; v.z *= inv; v.w *= inv;
    p[t] = v;
}

extern "C" void kernel_launch(void* const* d_in, const int* in_sizes, int n_in,
                              void* d_out, int out_size, void* d_ws, size_t ws_size,
                              hipStream_t stream) {
    const float* hidden = (const float*)d_in[0];   // [B,1,D]
    const float* enc    = (const float*)d_in[1];   // [B,S,D]
    const float* W      = (const float*)d_in[2];   // [D,D] (W[e,d])
    // d_in[3] = bias: per-batch constant on all logits -> softmax-invariant, unused.
    float* out  = (float*)d_out;                   // [B,1,S] fp32
    float* part = (float*)d_ws;                    // ECHUNKS*B*D floats = 512 KB

    compute_u_partial<<<dim3(ECHUNKS, BB), dim3(256), 0, stream>>>(hidden, W, part);
    scores_kernel<<<dim3(64, BB), dim3(256), 0, stream>>>(enc, part, out);
    softmax_kernel<<<dim3(BB), dim3(512), 0, stream>>>(out);
}